// Round 2
// baseline (954.028 us; speedup 1.0000x reference)
//
#include <hip/hip_runtime.h>
#include <hip/hip_bf16.h>

// GraphSAGE 2-layer forward. N=100000 nodes, E=1250000 edges, 64 -> 64 -> 32.
// Float tensors are float32 on device (NaN in round 1 proved they are NOT
// bf16-ified: f32 read as bf16 decodes stray NaN/Inf patterns). Indices int32.
// ws layout (fp32): deg[N] | agg[N*64] | h1[N*64]  ~= 51.6 MB.

#define NFEAT 64
#define NCLS  32

__global__ __launch_bounds__(256) void deg_kernel(const int* __restrict__ dst,
                                                  float* __restrict__ deg, int E) {
    int e = blockIdx.x * blockDim.x + threadIdx.x;
    if (e < E) atomicAdd(&deg[dst[e]], 1.0f);
}

// one thread per (edge, feature): coalesced gather + coalesced scatter-atomic
__global__ __launch_bounds__(256) void agg_kernel(const float* __restrict__ feats,
                                                  const int* __restrict__ src,
                                                  const int* __restrict__ dst,
                                                  float* __restrict__ agg, int E) {
    int tid = blockIdx.x * blockDim.x + threadIdx.x;
    if (tid >= E * NFEAT) return;
    int e = tid >> 6;
    int f = tid & 63;
    int s = src[e];
    int d = dst[e];
    atomicAdd(&agg[d * NFEAT + f], feats[s * NFEAT + f]);
}

// h1[n,c] = relu( x[n,:] @ Wself[:,c] + (agg[n,:]/max(deg,1)) @ Wneigh[:,c] + b[c] )
__global__ __launch_bounds__(256) void layer1_kernel(const float* __restrict__ x,
                                                     const float* __restrict__ agg,
                                                     const float* __restrict__ deg,
                                                     const float* __restrict__ Wself,
                                                     const float* __restrict__ Wneigh,
                                                     const float* __restrict__ b,
                                                     float* __restrict__ h1, int N) {
    int tid = blockIdx.x * blockDim.x + threadIdx.x;
    if (tid >= N * NFEAT) return;
    int n = tid >> 6;
    int c = tid & 63;
    float inv = 1.0f / fmaxf(deg[n], 1.0f);
    const float* xrow = x + n * NFEAT;
    const float* arow = agg + n * NFEAT;
    float acc = b[c];
    #pragma unroll
    for (int k = 0; k < NFEAT; ++k) {
        acc += xrow[k] * Wself[k * NFEAT + c];          // xrow[k]: wave-broadcast
        acc += (arow[k] * inv) * Wneigh[k * NFEAT + c]; // W: coalesced, L1-resident
    }
    h1[tid] = fmaxf(acc, 0.0f);
}

// out[n,c] = h1[n,:] @ Wself2[:,c] + (agg[n,:]/max(deg,1)) @ Wneigh2[:,c] + b2[c]
__global__ __launch_bounds__(256) void layer2_kernel(const float* __restrict__ h1,
                                                     const float* __restrict__ agg,
                                                     const float* __restrict__ deg,
                                                     const float* __restrict__ Wself,
                                                     const float* __restrict__ Wneigh,
                                                     const float* __restrict__ b,
                                                     float* __restrict__ out, int N) {
    int tid = blockIdx.x * blockDim.x + threadIdx.x;
    if (tid >= N * NCLS) return;
    int n = tid / NCLS;
    int c = tid % NCLS;
    float inv = 1.0f / fmaxf(deg[n], 1.0f);
    const float* hrow = h1 + n * NFEAT;
    const float* arow = agg + n * NFEAT;
    float acc = b[c];
    #pragma unroll
    for (int k = 0; k < NFEAT; ++k) {
        acc += hrow[k] * Wself[k * NCLS + c];
        acc += (arow[k] * inv) * Wneigh[k * NCLS + c];
    }
    out[tid] = acc;
}

extern "C" void kernel_launch(void* const* d_in, const int* in_sizes, int n_in,
                              void* d_out, int out_size, void* d_ws, size_t ws_size,
                              hipStream_t stream) {
    const float* x        = (const float*)d_in[0];
    const int*   src      = (const int*)d_in[1];
    const int*   dst      = (const int*)d_in[2];
    const float* W_self1  = (const float*)d_in[3];
    const float* W_neigh1 = (const float*)d_in[4];
    const float* b1       = (const float*)d_in[5];
    const float* W_self2  = (const float*)d_in[6];
    const float* W_neigh2 = (const float*)d_in[7];
    const float* b2       = (const float*)d_in[8];
    float* out = (float*)d_out;

    const int N = in_sizes[0] / NFEAT;   // 100000
    const int E = in_sizes[1];           // 1250000

    float* deg = (float*)d_ws;
    float* agg = deg + N;
    float* h1  = agg + (size_t)N * NFEAT;

    // zero deg + agg (contiguous)
    hipMemsetAsync(deg, 0, (size_t)(N + N * NFEAT) * sizeof(float), stream);

    deg_kernel<<<(E + 255) / 256, 256, 0, stream>>>(dst, deg, E);

    int agg_threads = E * NFEAT;  // 80M
    agg_kernel<<<(agg_threads + 255) / 256, 256, 0, stream>>>(x, src, dst, agg, E);

    layer1_kernel<<<(N * NFEAT + 255) / 256, 256, 0, stream>>>(x, agg, deg, W_self1, W_neigh1, b1, h1, N);

    hipMemsetAsync(agg, 0, (size_t)N * NFEAT * sizeof(float), stream);

    agg_kernel<<<(agg_threads + 255) / 256, 256, 0, stream>>>(h1, src, dst, agg, E);

    layer2_kernel<<<(N * NCLS + 255) / 256, 256, 0, stream>>>(h1, agg, deg, W_self2, W_neigh2, b2, out, N);
}

// Round 3
// 589.471 us; speedup vs baseline: 1.6184x; 1.6184x over previous
//
#include <hip/hip_runtime.h>
#include <hip/hip_bf16.h>

// GraphSAGE 2-layer forward. N=100000, E=1250000, 64 -> 64 -> 32, fp32.
//
// Fast path (CSR, no f32 atomics):
//   counts -> hist(dst) -> scan -> scatter => CSR(row_start, csr_src)
//   dense1: xs = x@Ws1+b1, t1 = x@Wn1          (LDS-staged W, 16 nodes/block)
//   agg64 : h1 = relu(xs + mean_n(t1[src]))    (wave per node, in-place on xs)
//   dense2: st2 = [h1@Ws2+b2 | h1@Wn2]         (packed 64-wide rows)
//   agg32 : out = st2[:, :32] + mean_n(st2[src, 32:])
// Linearity: segment_sum(h[src])@W == segment_sum((h@W)[src]) -- transform first.
//
// ws need: ints(row_start N+8, bsums 1024, cursor N, csr_src E) + 2 x N*64 f32
//          ~= 57.0 MB. Falls back to round-2 atomic path if ws_size too small.

#define NF 64
#define NC 32
#define SB 256   // scan block elems
#define NB 16    // nodes per block in dense kernels

// ---------------- CSR build ----------------

__global__ __launch_bounds__(256) void hist_kernel(const int* __restrict__ dst,
                                                   int* __restrict__ counts, int E) {
    int e = blockIdx.x * blockDim.x + threadIdx.x;
    if (e < E) atomicAdd(&counts[dst[e]], 1);
}

__global__ __launch_bounds__(SB) void scan_block_kernel(const int* __restrict__ counts,
                                                        int* __restrict__ excl,
                                                        int* __restrict__ bsums, int N) {
    __shared__ int buf[SB];
    int i = blockIdx.x * SB + threadIdx.x;
    int v = (i < N) ? counts[i] : 0;
    buf[threadIdx.x] = v;
    __syncthreads();
    for (int off = 1; off < SB; off <<= 1) {
        int t = (threadIdx.x >= (unsigned)off) ? buf[threadIdx.x - off] : 0;
        __syncthreads();
        buf[threadIdx.x] += t;
        __syncthreads();
    }
    if (i < N) excl[i] = buf[threadIdx.x] - v;       // exclusive within block
    if (threadIdx.x == SB - 1) bsums[blockIdx.x] = buf[SB - 1];
}

__global__ __launch_bounds__(1024) void scan_tops_kernel(int* __restrict__ bsums, int nb) {
    __shared__ int buf[1024];
    int v = (threadIdx.x < (unsigned)nb) ? bsums[threadIdx.x] : 0;
    buf[threadIdx.x] = v;
    __syncthreads();
    for (int off = 1; off < 1024; off <<= 1) {
        int t = (threadIdx.x >= (unsigned)off) ? buf[threadIdx.x - off] : 0;
        __syncthreads();
        buf[threadIdx.x] += t;
        __syncthreads();
    }
    if (threadIdx.x < (unsigned)nb) bsums[threadIdx.x] = buf[threadIdx.x] - v;  // exclusive
}

__global__ __launch_bounds__(256) void scan_final_kernel(int* __restrict__ row_start,
                                                         const int* __restrict__ bsums,
                                                         int* __restrict__ cursor,
                                                         int N, int E) {
    int i = blockIdx.x * blockDim.x + threadIdx.x;
    if (i < N) {
        int r = row_start[i] + bsums[i >> 8];   // SB == 256
        row_start[i] = r;
        cursor[i] = r;
    }
    if (i == 0) row_start[N] = E;
}

__global__ __launch_bounds__(256) void scatter_kernel(const int* __restrict__ src,
                                                      const int* __restrict__ dst,
                                                      int* __restrict__ cursor,
                                                      int* __restrict__ csr_src, int E) {
    int e = blockIdx.x * blockDim.x + threadIdx.x;
    if (e < E) {
        int p = atomicAdd(&cursor[dst[e]], 1);
        csr_src[p] = src[e];
    }
}

// ---------------- dense layers (LDS-staged W) ----------------

// xs[n,c] = b[c] + sum_k x[n,k] Ws[k,c];  t1[n,c] = sum_k x[n,k] Wn[k,c]
__global__ __launch_bounds__(256) void dense1_kernel(const float* __restrict__ x,
                                                     const float* __restrict__ Ws,
                                                     const float* __restrict__ Wn,
                                                     const float* __restrict__ b,
                                                     float* __restrict__ xs,
                                                     float* __restrict__ t1, int N) {
    __shared__ float ws[NF * NF];
    __shared__ float wn[NF * NF];
    __shared__ float xr[NB][NF];
    for (int i = threadIdx.x; i < NF * NF; i += 256) { ws[i] = Ws[i]; wn[i] = Wn[i]; }
    int wid = threadIdx.x >> 6, lane = threadIdx.x & 63;
    int nbase = blockIdx.x * NB + wid * 4;
    #pragma unroll
    for (int j = 0; j < 4; ++j) {
        int n = nbase + j;
        xr[wid * 4 + j][lane] = (n < N) ? x[(size_t)n * NF + lane] : 0.f;
    }
    __syncthreads();
    float bias = b[lane];
    float accs[4] = {bias, bias, bias, bias};
    float accn[4] = {0.f, 0.f, 0.f, 0.f};
    #pragma unroll
    for (int k = 0; k < NF; ++k) {
        float wsv = ws[k * NF + lane];   // 2 lanes/bank: free
        float wnv = wn[k * NF + lane];
        #pragma unroll
        for (int j = 0; j < 4; ++j) {
            float xk = xr[wid * 4 + j][k];   // broadcast
            accs[j] += xk * wsv;
            accn[j] += xk * wnv;
        }
    }
    #pragma unroll
    for (int j = 0; j < 4; ++j) {
        int n = nbase + j;
        if (n < N) {
            xs[(size_t)n * NF + lane] = accs[j];
            t1[(size_t)n * NF + lane] = accn[j];
        }
    }
}

// st2[n, c<32]  = b2[c] + sum_k h1[n,k] Ws2[k,c]
// st2[n, 32+c]  =         sum_k h1[n,k] Wn2[k,c]
__global__ __launch_bounds__(256) void dense2_kernel(const float* __restrict__ h1,
                                                     const float* __restrict__ Ws,
                                                     const float* __restrict__ Wn,
                                                     const float* __restrict__ b,
                                                     float* __restrict__ st2, int N) {
    __shared__ float w2[NF * NF];         // packed [k][c<32 -> Ws | 32+c -> Wn]
    __shared__ float xr[NB][NF];
    for (int i = threadIdx.x; i < NF * NC; i += 256) {
        int k = i >> 5, c = i & 31;
        w2[k * NF + c] = Ws[i];
        w2[k * NF + 32 + c] = Wn[i];
    }
    int wid = threadIdx.x >> 6, lane = threadIdx.x & 63;
    int nbase = blockIdx.x * NB + wid * 4;
    #pragma unroll
    for (int j = 0; j < 4; ++j) {
        int n = nbase + j;
        xr[wid * 4 + j][lane] = (n < N) ? h1[(size_t)n * NF + lane] : 0.f;
    }
    __syncthreads();
    float binit = (lane < 32) ? b[lane] : 0.f;
    float acc[4] = {binit, binit, binit, binit};
    #pragma unroll
    for (int k = 0; k < NF; ++k) {
        float wv = w2[k * NF + lane];
        #pragma unroll
        for (int j = 0; j < 4; ++j) acc[j] += xr[wid * 4 + j][k] * wv;
    }
    #pragma unroll
    for (int j = 0; j < 4; ++j) {
        int n = nbase + j;
        if (n < N) st2[(size_t)n * NF + lane] = acc[j];
    }
}

// ---------------- CSR aggregation (gather-only) ----------------

// h1[n,f] = relu(xs[n,f] + (sum_{s in in(n)} t1[s,f]) / max(deg,1)) ; in-place on xs
__global__ __launch_bounds__(256) void agg_mean64_kernel(const float* __restrict__ t1,
                                                         float* xs_io,
                                                         const int* __restrict__ row_start,
                                                         const int* __restrict__ csr_src, int N) {
    int gw = (blockIdx.x * blockDim.x + threadIdx.x) >> 6;   // wave per node
    int lane = threadIdx.x & 63;
    if (gw >= N) return;
    int beg = row_start[gw], end = row_start[gw + 1];
    float a0 = 0.f, a1 = 0.f;
    int j = beg;
    for (; j + 1 < end; j += 2) {
        int s0 = csr_src[j], s1 = csr_src[j + 1];
        a0 += t1[(size_t)s0 * NF + lane];
        a1 += t1[(size_t)s1 * NF + lane];
    }
    if (j < end) a0 += t1[(size_t)csr_src[j] * NF + lane];
    float inv = 1.0f / fmaxf((float)(end - beg), 1.0f);
    size_t o = (size_t)gw * NF + lane;
    float v = xs_io[o] + (a0 + a1) * inv;
    xs_io[o] = fmaxf(v, 0.f);
}

// out[n,c] = st2[n,c] + (sum_s st2[s,32+c]) / max(deg,1) ; 2 nodes per wave
__global__ __launch_bounds__(256) void agg_mean32_kernel(const float* __restrict__ st2,
                                                         const int* __restrict__ row_start,
                                                         const int* __restrict__ csr_src,
                                                         float* __restrict__ out, int N) {
    int gw = (blockIdx.x * blockDim.x + threadIdx.x) >> 6;
    int lane = threadIdx.x & 63;
    int half = lane >> 5, c = lane & 31;
    int n = gw * 2 + half;
    if (n >= N) return;
    int beg = row_start[n], end = row_start[n + 1];
    float a0 = 0.f, a1 = 0.f;
    int j = beg;
    for (; j + 1 < end; j += 2) {
        int s0 = csr_src[j], s1 = csr_src[j + 1];
        a0 += st2[(size_t)s0 * NF + 32 + c];
        a1 += st2[(size_t)s1 * NF + 32 + c];
    }
    if (j < end) a0 += st2[(size_t)csr_src[j] * NF + 32 + c];
    float inv = 1.0f / fmaxf((float)(end - beg), 1.0f);
    out[(size_t)n * NC + c] = st2[(size_t)n * NF + c] + (a0 + a1) * inv;
}

// ---------------- fallback (round-2 atomic path) ----------------

__global__ __launch_bounds__(256) void deg_kernel(const int* __restrict__ dst,
                                                  float* __restrict__ deg, int E) {
    int e = blockIdx.x * blockDim.x + threadIdx.x;
    if (e < E) atomicAdd(&deg[dst[e]], 1.0f);
}

__global__ __launch_bounds__(256) void agg_atomic_kernel(const float* __restrict__ feats,
                                                         const int* __restrict__ src,
                                                         const int* __restrict__ dst,
                                                         float* __restrict__ agg, int E) {
    int tid = blockIdx.x * blockDim.x + threadIdx.x;
    if (tid >= E * NF) return;
    int e = tid >> 6, f = tid & 63;
    atomicAdd(&agg[(size_t)dst[e] * NF + f], feats[(size_t)src[e] * NF + f]);
}

__global__ __launch_bounds__(256) void layer1_fb_kernel(const float* __restrict__ x,
                                                        const float* __restrict__ agg,
                                                        const float* __restrict__ deg,
                                                        const float* __restrict__ Wself,
                                                        const float* __restrict__ Wneigh,
                                                        const float* __restrict__ b,
                                                        float* __restrict__ h1, int N) {
    int tid = blockIdx.x * blockDim.x + threadIdx.x;
    if (tid >= N * NF) return;
    int n = tid >> 6, c = tid & 63;
    float inv = 1.0f / fmaxf(deg[n], 1.0f);
    const float* xrow = x + (size_t)n * NF;
    const float* arow = agg + (size_t)n * NF;
    float acc = b[c];
    #pragma unroll
    for (int k = 0; k < NF; ++k) {
        acc += xrow[k] * Wself[k * NF + c];
        acc += (arow[k] * inv) * Wneigh[k * NF + c];
    }
    h1[tid] = fmaxf(acc, 0.f);
}

__global__ __launch_bounds__(256) void layer2_fb_kernel(const float* __restrict__ h1,
                                                        const float* __restrict__ agg,
                                                        const float* __restrict__ deg,
                                                        const float* __restrict__ Wself,
                                                        const float* __restrict__ Wneigh,
                                                        const float* __restrict__ b,
                                                        float* __restrict__ out, int N) {
    int tid = blockIdx.x * blockDim.x + threadIdx.x;
    if (tid >= N * NC) return;
    int n = tid / NC, c = tid % NC;
    float inv = 1.0f / fmaxf(deg[n], 1.0f);
    const float* hrow = h1 + (size_t)n * NF;
    const float* arow = agg + (size_t)n * NF;
    float acc = b[c];
    #pragma unroll
    for (int k = 0; k < NF; ++k) {
        acc += hrow[k] * Wself[k * NC + c];
        acc += (arow[k] * inv) * Wneigh[k * NC + c];
    }
    out[tid] = acc;
}

// ---------------- launch ----------------

extern "C" void kernel_launch(void* const* d_in, const int* in_sizes, int n_in,
                              void* d_out, int out_size, void* d_ws, size_t ws_size,
                              hipStream_t stream) {
    const float* x        = (const float*)d_in[0];
    const int*   src      = (const int*)d_in[1];
    const int*   dst      = (const int*)d_in[2];
    const float* W_self1  = (const float*)d_in[3];
    const float* W_neigh1 = (const float*)d_in[4];
    const float* b1       = (const float*)d_in[5];
    const float* W_self2  = (const float*)d_in[6];
    const float* W_neigh2 = (const float*)d_in[7];
    const float* b2       = (const float*)d_in[8];
    float* out = (float*)d_out;

    const int N = in_sizes[0] / NF;   // 100000
    const int E = in_sizes[1];        // 1250000
    const int nb = (N + SB - 1) / SB; // scan blocks (391), must be <= 1024

    // ws layout (fast path), all segment sizes multiples of 4 elems -> 16B aligned
    const size_t rsPad   = ((size_t)N + 8) & ~7ull;   // row_start [N+1] padded
    int* row_start = (int*)d_ws;
    int* bsums     = row_start + rsPad;               // [1024]
    int* cursor    = bsums + 1024;                    // [N] (also scratch counts)
    int* csr_src   = cursor + ((size_t)(N + 7) & ~7ull);
    float* bufA    = (float*)(csr_src + (((size_t)E + 7) & ~7ull)); // xs / h1
    float* bufB    = bufA + (size_t)N * NF;                         // t1 / st2
    size_t need = (size_t)((char*)(bufB + (size_t)N * NF) - (char*)d_ws);

    if (ws_size >= need && nb <= 1024) {
        // ---- CSR build ----
        hipMemsetAsync(cursor, 0, (size_t)N * sizeof(int), stream);   // counts
        hist_kernel<<<(E + 255) / 256, 256, 0, stream>>>(dst, cursor, E);
        scan_block_kernel<<<nb, SB, 0, stream>>>(cursor, row_start, bsums, N);
        scan_tops_kernel<<<1, 1024, 0, stream>>>(bsums, nb);
        scan_final_kernel<<<(N + 255) / 256, 256, 0, stream>>>(row_start, bsums, cursor, N, E);
        scatter_kernel<<<(E + 255) / 256, 256, 0, stream>>>(src, dst, cursor, csr_src, E);

        // ---- layer 1 ----
        dense1_kernel<<<(N + NB - 1) / NB, 256, 0, stream>>>(x, W_self1, W_neigh1, b1,
                                                             bufA, bufB, N);
        agg_mean64_kernel<<<((N * 64) + 255) / 256, 256, 0, stream>>>(bufB, bufA,
                                                                      row_start, csr_src, N);
        // ---- layer 2 ----
        dense2_kernel<<<(N + NB - 1) / NB, 256, 0, stream>>>(bufA, W_self2, W_neigh2, b2,
                                                             bufB, N);
        int waves2 = (N + 1) / 2;
        agg_mean32_kernel<<<((waves2 * 64) + 255) / 256, 256, 0, stream>>>(bufB, row_start,
                                                                           csr_src, out, N);
    } else {
        // ---- fallback: round-2 atomic path (needs ~51.6 MB) ----
        float* deg = (float*)d_ws;
        float* agg = deg + N;
        float* h1  = agg + (size_t)N * NF;
        hipMemsetAsync(deg, 0, (size_t)(N + (size_t)N * NF) * sizeof(float), stream);
        deg_kernel<<<(E + 255) / 256, 256, 0, stream>>>(dst, deg, E);
        int at = E * NF;
        agg_atomic_kernel<<<(at + 255) / 256, 256, 0, stream>>>(x, src, dst, agg, E);
        layer1_fb_kernel<<<(N * NF + 255) / 256, 256, 0, stream>>>(x, agg, deg, W_self1,
                                                                   W_neigh1, b1, h1, N);
        hipMemsetAsync(agg, 0, (size_t)N * NF * sizeof(float), stream);
        agg_atomic_kernel<<<(at + 255) / 256, 256, 0, stream>>>(h1, src, dst, agg, E);
        layer2_fb_kernel<<<(N * NC + 255) / 256, 256, 0, stream>>>(h1, agg, deg, W_self2,
                                                                   W_neigh2, b2, out, N);
    }
}

// Round 4
// 387.608 us; speedup vs baseline: 2.4613x; 1.5208x over previous
//
#include <hip/hip_runtime.h>
#include <hip/hip_bf16.h>

// GraphSAGE 2-layer forward. N=100000, E=1250000, 64 -> 64 -> 32, fp32.
//
// Round-4: MFMA dense layers (split-bf16 = fp32-accurate: xh@Wh + xl@Wh + xh@Wl),
// CSR gather-only aggregation with 4x/8x row-parallel float4 gathers.
//
//   CSR build: hist -> scan -> scatter
//   wprep  : W1cat/W2cat transposed + split to bf16 hi/lo, [n][72] pad (global)
//   dense1 : bufA = x@Ws1+b1, bufB = x@Wn1        (MFMA 16x16x32, 32 rows/wave)
//   agg64  : bufA = relu(bufA + mean_n bufB[src]) (wave/node, 4 rows in flight)
//   dense2 : bufB = [h1@Ws2+b2 | h1@Wn2]          (packed 64-wide)
//   agg32  : out  = bufB[:,:32] + mean_n bufB[src,32:]

#define NF 64
#define SB 256

typedef __attribute__((ext_vector_type(8))) short short8;
typedef __attribute__((ext_vector_type(4))) float floatx4;

__device__ __forceinline__ short bf16hi(float v) {
    __hip_bfloat16 h = __float2bfloat16(v);
    return *(short*)&h;
}
__device__ __forceinline__ float bf2f(short s) {
    __hip_bfloat16 h = *(__hip_bfloat16*)&s;
    return __bfloat162float(h);
}

// ---------------- CSR build ----------------

__global__ __launch_bounds__(256) void hist_kernel(const int* __restrict__ dst,
                                                   int* __restrict__ counts, int E) {
    int e = blockIdx.x * blockDim.x + threadIdx.x;
    if (e < E) atomicAdd(&counts[dst[e]], 1);
}

__global__ __launch_bounds__(SB) void scan_block_kernel(const int* __restrict__ counts,
                                                        int* __restrict__ excl,
                                                        int* __restrict__ bsums, int N) {
    __shared__ int buf[SB];
    int i = blockIdx.x * SB + threadIdx.x;
    int v = (i < N) ? counts[i] : 0;
    buf[threadIdx.x] = v;
    __syncthreads();
    for (int off = 1; off < SB; off <<= 1) {
        int t = (threadIdx.x >= (unsigned)off) ? buf[threadIdx.x - off] : 0;
        __syncthreads();
        buf[threadIdx.x] += t;
        __syncthreads();
    }
    if (i < N) excl[i] = buf[threadIdx.x] - v;
    if (threadIdx.x == SB - 1) bsums[blockIdx.x] = buf[SB - 1];
}

__global__ __launch_bounds__(1024) void scan_tops_kernel(int* __restrict__ bsums, int nb) {
    __shared__ int buf[1024];
    int v = (threadIdx.x < (unsigned)nb) ? bsums[threadIdx.x] : 0;
    buf[threadIdx.x] = v;
    __syncthreads();
    for (int off = 1; off < 1024; off <<= 1) {
        int t = (threadIdx.x >= (unsigned)off) ? buf[threadIdx.x - off] : 0;
        __syncthreads();
        buf[threadIdx.x] += t;
        __syncthreads();
    }
    if (threadIdx.x < (unsigned)nb) bsums[threadIdx.x] = buf[threadIdx.x] - v;
}

__global__ __launch_bounds__(256) void scan_final_kernel(int* __restrict__ row_start,
                                                         const int* __restrict__ bsums,
                                                         int* __restrict__ cursor,
                                                         int N, int E) {
    int i = blockIdx.x * blockDim.x + threadIdx.x;
    if (i < N) {
        int r = row_start[i] + bsums[i >> 8];   // SB == 256
        row_start[i] = r;
        cursor[i] = r;
    }
    if (i == 0) row_start[N] = E;
}

__global__ __launch_bounds__(256) void scatter_kernel(const int* __restrict__ src,
                                                      const int* __restrict__ dst,
                                                      int* __restrict__ cursor,
                                                      int* __restrict__ csr_src, int E) {
    int e = blockIdx.x * blockDim.x + threadIdx.x;
    if (e < E) {
        int p = atomicAdd(&cursor[dst[e]], 1);
        csr_src[p] = src[e];
    }
}

// ---------------- weight prep: transpose + split-bf16, [n][72] ----------------

__global__ __launch_bounds__(256) void wprep_kernel(const float* __restrict__ Ws1,
                                                    const float* __restrict__ Wn1,
                                                    const float* __restrict__ Ws2,
                                                    const float* __restrict__ Wn2,
                                                    unsigned short* __restrict__ wt1h,
                                                    unsigned short* __restrict__ wt1l,
                                                    unsigned short* __restrict__ wt2h,
                                                    unsigned short* __restrict__ wt2l) {
    int i = blockIdx.x * 256 + threadIdx.x;
    if (i < 128 * 64) {
        int n = i >> 6, k = i & 63;
        float v = (n < 64) ? Ws1[k * 64 + n] : Wn1[k * 64 + (n - 64)];
        short hi = bf16hi(v);
        wt1h[n * 72 + k] = (unsigned short)hi;
        wt1l[n * 72 + k] = (unsigned short)bf16hi(v - bf2f(hi));
    } else if (i < 128 * 64 + 64 * 64) {
        int j = i - 128 * 64;
        int n = j >> 6, k = j & 63;
        float v = (n < 32) ? Ws2[k * 32 + n] : Wn2[k * 32 + (n - 32)];
        short hi = bf16hi(v);
        wt2h[n * 72 + k] = (unsigned short)hi;
        wt2l[n * 72 + k] = (unsigned short)bf16hi(v - bf2f(hi));
    }
}

// ---------------- MFMA dense: [N][64] @ [64][NT*16] -> split outputs ----------
// A layout (verified m120): A[m=lane&15][k=(lane>>4)*8+j]
// C/D layout (verified m89): col=lane&15, row=(lane>>4)*4+reg
// 32 rows/wave, 128 rows/block (4 waves). B frags read from global (L1/L2-hot).

template<int NT, int BIAST>
__global__ __launch_bounds__(256) void dense_mfma_kernel(
        const float* __restrict__ X,                 // [N][64]
        const unsigned short* __restrict__ wh,       // [NT*16][72] bf16-hi bits
        const unsigned short* __restrict__ wl,       // [NT*16][72] bf16-lo bits
        const float* __restrict__ bias,              // [BIAST*16]
        float* __restrict__ outA, float* __restrict__ outB,  // row stride 64
        int N) {
    const int lane = threadIdx.x & 63;
    const int wid  = threadIdx.x >> 6;
    const int m = lane & 15, quad = lane >> 4;
    const int rowblk = blockIdx.x * 128 + wid * 32;

    floatx4 acc[2][NT];
    #pragma unroll
    for (int rt = 0; rt < 2; ++rt)
        #pragma unroll
        for (int t = 0; t < NT; ++t) acc[rt][t] = (floatx4)(0.f);

    short8 ah[2][2], al[2][2];   // [rowset][k-half]
    #pragma unroll
    for (int rt = 0; rt < 2; ++rt) {
        int r = rowblk + rt * 16 + m;
        if (r >= N) r = N - 1;                       // clamped load, store guarded
        const float* xp = X + (size_t)r * 64 + quad * 8;
        #pragma unroll
        for (int h = 0; h < 2; ++h) {
            floatx4 f0 = *(const floatx4*)(xp + h * 32);
            floatx4 f1 = *(const floatx4*)(xp + h * 32 + 4);
            short8 hi, lo;
            #pragma unroll
            for (int j = 0; j < 4; ++j) {
                short hv = bf16hi(f0[j]);
                hi[j] = hv; lo[j] = bf16hi(f0[j] - bf2f(hv));
                short hv2 = bf16hi(f1[j]);
                hi[4 + j] = hv2; lo[4 + j] = bf16hi(f1[j] - bf2f(hv2));
            }
            ah[rt][h] = hi; al[rt][h] = lo;
        }
    }

    #pragma unroll
    for (int t = 0; t < NT; ++t) {
        int n = t * 16 + m;
        const unsigned short* ph = wh + n * 72 + quad * 8;
        const unsigned short* pl = wl + n * 72 + quad * 8;
        #pragma unroll
        for (int h = 0; h < 2; ++h) {
            short8 bh = *(const short8*)(ph + h * 32);
            short8 bl = *(const short8*)(pl + h * 32);
            #pragma unroll
            for (int rt = 0; rt < 2; ++rt) {
                acc[rt][t] = __builtin_amdgcn_mfma_f32_16x16x32_bf16(ah[rt][h], bh, acc[rt][t], 0, 0, 0);
                acc[rt][t] = __builtin_amdgcn_mfma_f32_16x16x32_bf16(al[rt][h], bh, acc[rt][t], 0, 0, 0);
                acc[rt][t] = __builtin_amdgcn_mfma_f32_16x16x32_bf16(ah[rt][h], bl, acc[rt][t], 0, 0, 0);
            }
        }
    }

    #pragma unroll
    for (int rt = 0; rt < 2; ++rt) {
        #pragma unroll
        for (int t = 0; t < NT; ++t) {
            float* outp = (t < NT / 2) ? outA : outB;
            int col = (t & (NT / 2 - 1)) * 16 + m;
            float bv = (t < BIAST) ? bias[t * 16 + m] : 0.f;
            #pragma unroll
            for (int r4 = 0; r4 < 4; ++r4) {
                int row = rowblk + rt * 16 + quad * 4 + r4;
                if (row < N) outp[(size_t)row * 64 + col] = acc[rt][t][r4] + bv;
            }
        }
    }
}

// ---------------- CSR aggregation, row-parallel float4 gathers ----------------

// bufA[n] = relu(bufA[n] + mean_s bufB[s]); 4 neighbor rows in flight per wave
__global__ __launch_bounds__(256) void agg64_kernel(const float* __restrict__ t1,
                                                    float* __restrict__ xs_io,
                                                    const int* __restrict__ row_start,
                                                    const int* __restrict__ csr_src, int N) {
    int n = (blockIdx.x * blockDim.x + threadIdx.x) >> 6;
    if (n >= N) return;
    int lane = threadIdx.x & 63;
    int g = lane >> 4, c = lane & 15;
    int beg = row_start[n], end = row_start[n + 1];
    floatx4 acc = (floatx4)(0.f);
    for (int j0 = beg; j0 < end; j0 += 4) {
        int j = j0 + g;
        if (j < end) {
            int s = csr_src[j];
            acc += *(const floatx4*)(t1 + (size_t)s * 64 + c * 4);
        }
    }
    #pragma unroll
    for (int i = 0; i < 4; ++i) {
        float v = acc[i];
        v += __shfl_xor(v, 16);
        v += __shfl_xor(v, 32);
        acc[i] = v;
    }
    if (g == 0) {
        float inv = 1.0f / fmaxf((float)(end - beg), 1.0f);
        size_t o = (size_t)n * 64 + c * 4;
        floatx4 xs = *(const floatx4*)(xs_io + o);
        floatx4 r;
        #pragma unroll
        for (int i = 0; i < 4; ++i) r[i] = fmaxf(xs[i] + acc[i] * inv, 0.f);
        *(floatx4*)(xs_io + o) = r;
    }
}

// out[n] = st2[n,:32] + mean_s st2[s,32:]; 8 neighbor rows in flight per wave
__global__ __launch_bounds__(256) void agg32_kernel(const float* __restrict__ st2,
                                                    const int* __restrict__ row_start,
                                                    const int* __restrict__ csr_src,
                                                    float* __restrict__ out, int N) {
    int n = (blockIdx.x * blockDim.x + threadIdx.x) >> 6;
    if (n >= N) return;
    int lane = threadIdx.x & 63;
    int g = lane >> 3, c = lane & 7;
    int beg = row_start[n], end = row_start[n + 1];
    floatx4 acc = (floatx4)(0.f);
    for (int j0 = beg; j0 < end; j0 += 8) {
        int j = j0 + g;
        if (j < end) {
            int s = csr_src[j];
            acc += *(const floatx4*)(st2 + (size_t)s * 64 + 32 + c * 4);
        }
    }
    #pragma unroll
    for (int i = 0; i < 4; ++i) {
        float v = acc[i];
        v += __shfl_xor(v, 8);
        v += __shfl_xor(v, 16);
        v += __shfl_xor(v, 32);
        acc[i] = v;
    }
    if (g == 0) {
        float inv = 1.0f / fmaxf((float)(end - beg), 1.0f);
        floatx4 sf = *(const floatx4*)(st2 + (size_t)n * 64 + c * 4);
        floatx4 r;
        #pragma unroll
        for (int i = 0; i < 4; ++i) r[i] = sf[i] + acc[i] * inv;
        *(floatx4*)(out + (size_t)n * 32 + c * 4) = r;
    }
}

// ---------------- fallback (round-2 atomic path) ----------------

__global__ __launch_bounds__(256) void deg_kernel(const int* __restrict__ dst,
                                                  float* __restrict__ deg, int E) {
    int e = blockIdx.x * blockDim.x + threadIdx.x;
    if (e < E) atomicAdd(&deg[dst[e]], 1.0f);
}

__global__ __launch_bounds__(256) void agg_atomic_kernel(const float* __restrict__ feats,
                                                         const int* __restrict__ src,
                                                         const int* __restrict__ dst,
                                                         float* __restrict__ agg, int E) {
    int tid = blockIdx.x * blockDim.x + threadIdx.x;
    if (tid >= E * NF) return;
    int e = tid >> 6, f = tid & 63;
    atomicAdd(&agg[(size_t)dst[e] * NF + f], feats[(size_t)src[e] * NF + f]);
}

__global__ __launch_bounds__(256) void layer1_fb_kernel(const float* __restrict__ x,
                                                        const float* __restrict__ agg,
                                                        const float* __restrict__ deg,
                                                        const float* __restrict__ Wself,
                                                        const float* __restrict__ Wneigh,
                                                        const float* __restrict__ b,
                                                        float* __restrict__ h1, int N) {
    int tid = blockIdx.x * blockDim.x + threadIdx.x;
    if (tid >= N * NF) return;
    int n = tid >> 6, c = tid & 63;
    float inv = 1.0f / fmaxf(deg[n], 1.0f);
    const float* xrow = x + (size_t)n * NF;
    const float* arow = agg + (size_t)n * NF;
    float acc = b[c];
    #pragma unroll
    for (int k = 0; k < NF; ++k) {
        acc += xrow[k] * Wself[k * NF + c];
        acc += (arow[k] * inv) * Wneigh[k * NF + c];
    }
    h1[tid] = fmaxf(acc, 0.f);
}

__global__ __launch_bounds__(256) void layer2_fb_kernel(const float* __restrict__ h1,
                                                        const float* __restrict__ agg,
                                                        const float* __restrict__ deg,
                                                        const float* __restrict__ Wself,
                                                        const float* __restrict__ Wneigh,
                                                        const float* __restrict__ b,
                                                        float* __restrict__ out, int N) {
    int tid = blockIdx.x * blockDim.x + threadIdx.x;
    if (tid >= N * 32) return;
    int n = tid >> 5, c = tid & 31;
    float inv = 1.0f / fmaxf(deg[n], 1.0f);
    const float* hrow = h1 + (size_t)n * NF;
    const float* arow = agg + (size_t)n * NF;
    float acc = b[c];
    #pragma unroll
    for (int k = 0; k < NF; ++k) {
        acc += hrow[k] * Wself[k * 32 + c];
        acc += (arow[k] * inv) * Wneigh[k * 32 + c];
    }
    out[tid] = acc;
}

// ---------------- launch ----------------

extern "C" void kernel_launch(void* const* d_in, const int* in_sizes, int n_in,
                              void* d_out, int out_size, void* d_ws, size_t ws_size,
                              hipStream_t stream) {
    const float* x        = (const float*)d_in[0];
    const int*   src      = (const int*)d_in[1];
    const int*   dst      = (const int*)d_in[2];
    const float* W_self1  = (const float*)d_in[3];
    const float* W_neigh1 = (const float*)d_in[4];
    const float* b1       = (const float*)d_in[5];
    const float* W_self2  = (const float*)d_in[6];
    const float* W_neigh2 = (const float*)d_in[7];
    const float* b2       = (const float*)d_in[8];
    float* out = (float*)d_out;

    const int N = in_sizes[0] / NF;   // 100000
    const int E = in_sizes[1];        // 1250000
    const int nb = (N + SB - 1) / SB; // 391, must be <= 1024

    // ws layout (fast path); every segment multiple of 32 B
    const size_t rsPad   = ((size_t)N + 8) & ~7ull;
    int* row_start = (int*)d_ws;
    int* bsums     = row_start + rsPad;               // [1024]
    int* cursor    = bsums + 1024;                    // [N] (counts scratch)
    int* csr_src   = cursor + (((size_t)N + 7) & ~7ull);
    unsigned short* wt1h = (unsigned short*)(csr_src + (((size_t)E + 7) & ~7ull));
    unsigned short* wt1l = wt1h + 128 * 72;
    unsigned short* wt2h = wt1l + 128 * 72;
    unsigned short* wt2l = wt2h + 64 * 72;
    float* bufA = (float*)(wt2l + 64 * 72);           // xs -> h1 (in place)
    float* bufB = bufA + (size_t)N * NF;              // t1 -> st2
    size_t need = (size_t)((char*)(bufB + (size_t)N * NF) - (char*)d_ws);

    if (ws_size >= need && nb <= 1024) {
        // CSR build
        hipMemsetAsync(cursor, 0, (size_t)N * sizeof(int), stream);
        hist_kernel<<<(E + 255) / 256, 256, 0, stream>>>(dst, cursor, E);
        scan_block_kernel<<<nb, SB, 0, stream>>>(cursor, row_start, bsums, N);
        scan_tops_kernel<<<1, 1024, 0, stream>>>(bsums, nb);
        scan_final_kernel<<<(N + 255) / 256, 256, 0, stream>>>(row_start, bsums, cursor, N, E);
        scatter_kernel<<<(E + 255) / 256, 256, 0, stream>>>(src, dst, cursor, csr_src, E);

        // weight prep (independent of CSR)
        wprep_kernel<<<(128 * 64 + 64 * 64 + 255) / 256, 256, 0, stream>>>(
            W_self1, W_neigh1, W_self2, W_neigh2, wt1h, wt1l, wt2h, wt2l);

        int dblocks = (N + 127) / 128;
        // layer 1
        dense_mfma_kernel<8, 4><<<dblocks, 256, 0, stream>>>(x, wt1h, wt1l, b1,
                                                             bufA, bufB, N);
        agg64_kernel<<<(N * 64 + 255) / 256, 256, 0, stream>>>(bufB, bufA,
                                                               row_start, csr_src, N);
        // layer 2 (packed out: cols 0-31 self+b2 -> bufB, cols 32-63 neigh -> bufB+32)
        dense_mfma_kernel<4, 2><<<dblocks, 256, 0, stream>>>(bufA, wt2h, wt2l, b2,
                                                             bufB, bufB + 32, N);
        agg32_kernel<<<(N * 64 + 255) / 256, 256, 0, stream>>>(bufB, row_start,
                                                               csr_src, out, N);
    } else {
        // fallback: atomic path (~51.6 MB)
        float* deg = (float*)d_ws;
        float* agg = deg + N;
        float* h1  = agg + (size_t)N * NF;
        hipMemsetAsync(deg, 0, (size_t)(N + (size_t)N * NF) * sizeof(float), stream);
        deg_kernel<<<(E + 255) / 256, 256, 0, stream>>>(dst, deg, E);
        int at = E * NF;
        agg_atomic_kernel<<<(at + 255) / 256, 256, 0, stream>>>(x, src, dst, agg, E);
        layer1_fb_kernel<<<(N * NF + 255) / 256, 256, 0, stream>>>(x, agg, deg, W_self1,
                                                                   W_neigh1, b1, h1, N);
        hipMemsetAsync(agg, 0, (size_t)N * NF * sizeof(float), stream);
        agg_atomic_kernel<<<(at + 255) / 256, 256, 0, stream>>>(h1, src, dst, agg, E);
        layer2_fb_kernel<<<(N * 32 + 255) / 256, 256, 0, stream>>>(h1, agg, deg, W_self2,
                                                                   W_neigh2, b2, out, N);
    }
}

// Round 5
// 358.461 us; speedup vs baseline: 2.6615x; 1.0813x over previous
//
#include <hip/hip_runtime.h>
#include <hip/hip_bf16.h>

// GraphSAGE 2-layer forward. N=100000, E=1250000, 64 -> 64 -> 32, fp32.
//
// Round-5: range-partitioned CSR build (kills 17x scatter write amplification),
// LDS-binned histogram, bf16 neighbor-transform buffers (halve gather traffic),
// wide agg waves (8/16 rows in flight, ushort8 loads, shfl butterflies).
//
//   hist(LDS bins) -> scan -> scatter(8 dst-ranges) => CSR
//   dense1 : bufA = x@Ws1+b1 (f32), t1n = bf16(x@Wn1)     (MFMA split-bf16)
//   agg64  : bufA = relu(bufA + mean_n t1n[src])
//   dense2 : s2 = h1@Ws2+b2 (f32), t2n = bf16(h1@Wn2)
//   agg32  : out = s2 + mean_n t2n[src]

#define NF 64
#define SB 256
#define RMAX 12544          // dst-range width (50176 B LDS bins)
#define HIST_CHUNKS 32
#define SCAT_CHUNKS 256

typedef __attribute__((ext_vector_type(8))) short short8;
typedef __attribute__((ext_vector_type(8))) unsigned short ushort8v;
typedef __attribute__((ext_vector_type(4))) float floatx4;

__device__ __forceinline__ short bf16hi(float v) {
    __hip_bfloat16 h = __float2bfloat16(v);
    return *(short*)&h;
}
__device__ __forceinline__ float bf2f(short s) {
    __hip_bfloat16 h = *(__hip_bfloat16*)&s;
    return __bfloat162float(h);
}
__device__ __forceinline__ float bits2f(unsigned short u) {
    unsigned int x = ((unsigned int)u) << 16;
    union { unsigned int i; float f; } c; c.i = x; return c.f;
}

// ---------------- CSR build ----------------

// LDS-binned histogram: grid (HIST_CHUNKS, nranges)
__global__ __launch_bounds__(256) void hist_lds_kernel(const int* __restrict__ dst,
                                                       int* __restrict__ counts, int E, int N) {
    __shared__ int bins[RMAX];
    for (int i = threadIdx.x; i < RMAX; i += 256) bins[i] = 0;
    __syncthreads();
    const int base = blockIdx.y * RMAX;
    const int CE = (E + HIST_CHUNKS - 1) / HIST_CHUNKS;
    const int beg = blockIdx.x * CE;
    const int end = min(E, beg + CE);
    for (int e = beg + threadIdx.x; e < end; e += 256) {
        unsigned rel = (unsigned)(dst[e] - base);
        if (rel < RMAX) atomicAdd(&bins[rel], 1);
    }
    __syncthreads();
    for (int i = threadIdx.x; i < RMAX; i += 256) {
        int v = bins[i];
        if (v && base + i < N) atomicAdd(&counts[base + i], v);
    }
}

__global__ __launch_bounds__(SB) void scan_block_kernel(const int* __restrict__ counts,
                                                        int* __restrict__ excl,
                                                        int* __restrict__ bsums, int N) {
    __shared__ int buf[SB];
    int i = blockIdx.x * SB + threadIdx.x;
    int v = (i < N) ? counts[i] : 0;
    buf[threadIdx.x] = v;
    __syncthreads();
    for (int off = 1; off < SB; off <<= 1) {
        int t = (threadIdx.x >= (unsigned)off) ? buf[threadIdx.x - off] : 0;
        __syncthreads();
        buf[threadIdx.x] += t;
        __syncthreads();
    }
    if (i < N) excl[i] = buf[threadIdx.x] - v;
    if (threadIdx.x == SB - 1) bsums[blockIdx.x] = buf[SB - 1];
}

__global__ __launch_bounds__(1024) void scan_tops_kernel(int* __restrict__ bsums, int nb) {
    __shared__ int buf[1024];
    int v = (threadIdx.x < (unsigned)nb) ? bsums[threadIdx.x] : 0;
    buf[threadIdx.x] = v;
    __syncthreads();
    for (int off = 1; off < 1024; off <<= 1) {
        int t = (threadIdx.x >= (unsigned)off) ? buf[threadIdx.x - off] : 0;
        __syncthreads();
        buf[threadIdx.x] += t;
        __syncthreads();
    }
    if (threadIdx.x < (unsigned)nb) bsums[threadIdx.x] = buf[threadIdx.x] - v;
}

__global__ __launch_bounds__(256) void scan_final_kernel(int* __restrict__ row_start,
                                                         const int* __restrict__ bsums,
                                                         int* __restrict__ cursor,
                                                         int N, int E) {
    int i = blockIdx.x * blockDim.x + threadIdx.x;
    if (i < N) {
        int r = row_start[i] + bsums[i >> 8];   // SB == 256
        row_start[i] = r;
        cursor[i] = r;
    }
    if (i == 0) row_start[N] = E;
}

// Range-partitioned scatter: grid (SCAT_CHUNKS, nranges); each block handles
// only dst in [blockIdx.y*RMAX, +RMAX) -> csr writes localized to ~625 KB.
__global__ __launch_bounds__(256) void scatter_part_kernel(const int* __restrict__ src,
                                                           const int* __restrict__ dst,
                                                           int* __restrict__ cursor,
                                                           int* __restrict__ csr_src, int E) {
    const int base = blockIdx.y * RMAX;
    const int CE = (E + SCAT_CHUNKS - 1) / SCAT_CHUNKS;
    const int beg = blockIdx.x * CE;
    const int end = min(E, beg + CE);
    for (int e = beg + threadIdx.x; e < end; e += 256) {
        int d = dst[e];
        unsigned rel = (unsigned)(d - base);
        if (rel < RMAX) {
            int p = atomicAdd(&cursor[d], 1);
            csr_src[p] = src[e];
        }
    }
}

// ---------------- weight prep: transpose + split-bf16, [n][72] ----------------

__global__ __launch_bounds__(256) void wprep_kernel(const float* __restrict__ Ws1,
                                                    const float* __restrict__ Wn1,
                                                    const float* __restrict__ Ws2,
                                                    const float* __restrict__ Wn2,
                                                    unsigned short* __restrict__ wt1h,
                                                    unsigned short* __restrict__ wt1l,
                                                    unsigned short* __restrict__ wt2h,
                                                    unsigned short* __restrict__ wt2l) {
    int i = blockIdx.x * 256 + threadIdx.x;
    if (i < 128 * 64) {
        int n = i >> 6, k = i & 63;
        float v = (n < 64) ? Ws1[k * 64 + n] : Wn1[k * 64 + (n - 64)];
        short hi = bf16hi(v);
        wt1h[n * 72 + k] = (unsigned short)hi;
        wt1l[n * 72 + k] = (unsigned short)bf16hi(v - bf2f(hi));
    } else if (i < 128 * 64 + 64 * 64) {
        int j = i - 128 * 64;
        int n = j >> 6, k = j & 63;
        float v = (n < 32) ? Ws2[k * 32 + n] : Wn2[k * 32 + (n - 32)];
        short hi = bf16hi(v);
        wt2h[n * 72 + k] = (unsigned short)hi;
        wt2l[n * 72 + k] = (unsigned short)bf16hi(v - bf2f(hi));
    }
}

// ---------------- MFMA dense: [N][64] @ [64][NT*16] ----------
// A layout: A[m=lane&15][k=(lane>>4)*8+j]; C/D: col=lane&15, row=(lane>>4)*4+reg.
// Tiles t<NSELF -> f32 out + bias; t>=NSELF -> bf16 out (neighbor transform).

template<int NT, int NSELF>
__global__ __launch_bounds__(256) void dense_mfma_kernel(
        const float* __restrict__ X,                 // [N][64]
        const unsigned short* __restrict__ wh,       // [NT*16][72] bf16-hi
        const unsigned short* __restrict__ wl,       // [NT*16][72] bf16-lo
        const float* __restrict__ bias,              // [NSELF*16]
        float* __restrict__ outA,                    // row stride sA
        unsigned short* __restrict__ outB,           // row stride sB (bf16 bits)
        int sA, int sB, int N) {
    const int lane = threadIdx.x & 63;
    const int wid  = threadIdx.x >> 6;
    const int m = lane & 15, quad = lane >> 4;
    const int rowblk = blockIdx.x * 128 + wid * 32;

    floatx4 acc[2][NT];
    #pragma unroll
    for (int rt = 0; rt < 2; ++rt)
        #pragma unroll
        for (int t = 0; t < NT; ++t) acc[rt][t] = (floatx4)(0.f);

    short8 ah[2][2], al[2][2];   // [rowset][k-half]
    #pragma unroll
    for (int rt = 0; rt < 2; ++rt) {
        int r = rowblk + rt * 16 + m;
        if (r >= N) r = N - 1;                       // clamped load, store guarded
        const float* xp = X + (size_t)r * 64 + quad * 8;
        #pragma unroll
        for (int h = 0; h < 2; ++h) {
            floatx4 f0 = *(const floatx4*)(xp + h * 32);
            floatx4 f1 = *(const floatx4*)(xp + h * 32 + 4);
            short8 hi, lo;
            #pragma unroll
            for (int j = 0; j < 4; ++j) {
                short hv = bf16hi(f0[j]);
                hi[j] = hv; lo[j] = bf16hi(f0[j] - bf2f(hv));
                short hv2 = bf16hi(f1[j]);
                hi[4 + j] = hv2; lo[4 + j] = bf16hi(f1[j] - bf2f(hv2));
            }
            ah[rt][h] = hi; al[rt][h] = lo;
        }
    }

    #pragma unroll
    for (int t = 0; t < NT; ++t) {
        int n = t * 16 + m;
        const unsigned short* ph = wh + n * 72 + quad * 8;
        const unsigned short* pl = wl + n * 72 + quad * 8;
        #pragma unroll
        for (int h = 0; h < 2; ++h) {
            short8 bh = *(const short8*)(ph + h * 32);
            short8 bl = *(const short8*)(pl + h * 32);
            #pragma unroll
            for (int rt = 0; rt < 2; ++rt) {
                acc[rt][t] = __builtin_amdgcn_mfma_f32_16x16x32_bf16(ah[rt][h], bh, acc[rt][t], 0, 0, 0);
                acc[rt][t] = __builtin_amdgcn_mfma_f32_16x16x32_bf16(al[rt][h], bh, acc[rt][t], 0, 0, 0);
                acc[rt][t] = __builtin_amdgcn_mfma_f32_16x16x32_bf16(ah[rt][h], bl, acc[rt][t], 0, 0, 0);
            }
        }
    }

    #pragma unroll
    for (int rt = 0; rt < 2; ++rt) {
        #pragma unroll
        for (int t = 0; t < NT; ++t) {
            #pragma unroll
            for (int r4 = 0; r4 < 4; ++r4) {
                int row = rowblk + rt * 16 + quad * 4 + r4;
                if (row < N) {
                    if (t < NSELF) {
                        int col = t * 16 + m;
                        outA[(size_t)row * sA + col] = acc[rt][t][r4] + bias[col];
                    } else {
                        int col = (t - NSELF) * 16 + m;
                        outB[(size_t)row * sB + col] = (unsigned short)bf16hi(acc[rt][t][r4]);
                    }
                }
            }
        }
    }
}

// ---------------- CSR aggregation (bf16 gathers, wide waves) ----------------

// bufA[n] = relu(bufA[n] + mean_s t1n[s]); 8 groups of 8 lanes, 8 rows in flight
__global__ __launch_bounds__(256) void agg64_kernel(const unsigned short* __restrict__ t1n,
                                                    float* __restrict__ xs_io,
                                                    const int* __restrict__ row_start,
                                                    const int* __restrict__ csr_src, int N) {
    int n = (blockIdx.x * blockDim.x + threadIdx.x) >> 6;
    if (n >= N) return;
    int lane = threadIdx.x & 63;
    int g = lane >> 3, c = lane & 7;                 // lane covers feats c*8..c*8+7
    int beg = row_start[n], end = row_start[n + 1];
    float acc[8] = {0.f, 0.f, 0.f, 0.f, 0.f, 0.f, 0.f, 0.f};
    for (int j0 = beg; j0 < end; j0 += 8) {
        int j = j0 + g;
        if (j < end) {
            int s = csr_src[j];
            ushort8v u = *(const ushort8v*)(t1n + (size_t)s * 64 + c * 8);
            #pragma unroll
            for (int i = 0; i < 8; ++i) acc[i] += bits2f(u[i]);
        }
    }
    #pragma unroll
    for (int i = 0; i < 8; ++i) {
        float v = acc[i];
        v += __shfl_xor(v, 8);
        v += __shfl_xor(v, 16);
        v += __shfl_xor(v, 32);
        acc[i] = v;
    }
    if (g == 0) {
        float inv = 1.0f / fmaxf((float)(end - beg), 1.0f);
        size_t o = (size_t)n * 64 + c * 8;
        floatx4 x0 = *(const floatx4*)(xs_io + o);
        floatx4 x1 = *(const floatx4*)(xs_io + o + 4);
        floatx4 r0, r1;
        #pragma unroll
        for (int i = 0; i < 4; ++i) {
            r0[i] = fmaxf(x0[i] + acc[i] * inv, 0.f);
            r1[i] = fmaxf(x1[i] + acc[4 + i] * inv, 0.f);
        }
        *(floatx4*)(xs_io + o) = r0;
        *(floatx4*)(xs_io + o + 4) = r1;
    }
}

// out[n] = s2[n] + mean_s t2n[s]; 16 groups of 4 lanes, 16 rows in flight
__global__ __launch_bounds__(256) void agg32_kernel(const float* __restrict__ s2,
                                                    const unsigned short* __restrict__ t2n,
                                                    const int* __restrict__ row_start,
                                                    const int* __restrict__ csr_src,
                                                    float* __restrict__ out, int N) {
    int n = (blockIdx.x * blockDim.x + threadIdx.x) >> 6;
    if (n >= N) return;
    int lane = threadIdx.x & 63;
    int g = lane >> 2, c = lane & 3;                 // lane covers feats c*8..c*8+7
    int beg = row_start[n], end = row_start[n + 1];
    float acc[8] = {0.f, 0.f, 0.f, 0.f, 0.f, 0.f, 0.f, 0.f};
    for (int j0 = beg; j0 < end; j0 += 16) {
        int j = j0 + g;
        if (j < end) {
            int s = csr_src[j];
            ushort8v u = *(const ushort8v*)(t2n + (size_t)s * 32 + c * 8);
            #pragma unroll
            for (int i = 0; i < 8; ++i) acc[i] += bits2f(u[i]);
        }
    }
    #pragma unroll
    for (int i = 0; i < 8; ++i) {
        float v = acc[i];
        v += __shfl_xor(v, 4);
        v += __shfl_xor(v, 8);
        v += __shfl_xor(v, 16);
        v += __shfl_xor(v, 32);
        acc[i] = v;
    }
    if (g == 0) {
        float inv = 1.0f / fmaxf((float)(end - beg), 1.0f);
        size_t o = (size_t)n * 32 + c * 8;
        floatx4 s0 = *(const floatx4*)(s2 + o);
        floatx4 s1 = *(const floatx4*)(s2 + o + 4);
        floatx4 r0, r1;
        #pragma unroll
        for (int i = 0; i < 4; ++i) {
            r0[i] = s0[i] + acc[i] * inv;
            r1[i] = s1[i] + acc[4 + i] * inv;
        }
        *(floatx4*)(out + o) = r0;
        *(floatx4*)(out + o + 4) = r1;
    }
}

// ---------------- fallback (round-2 atomic path) ----------------

__global__ __launch_bounds__(256) void deg_kernel(const int* __restrict__ dst,
                                                  float* __restrict__ deg, int E) {
    int e = blockIdx.x * blockDim.x + threadIdx.x;
    if (e < E) atomicAdd(&deg[dst[e]], 1.0f);
}

__global__ __launch_bounds__(256) void agg_atomic_kernel(const float* __restrict__ feats,
                                                         const int* __restrict__ src,
                                                         const int* __restrict__ dst,
                                                         float* __restrict__ agg, int E) {
    int tid = blockIdx.x * blockDim.x + threadIdx.x;
    if (tid >= E * NF) return;
    int e = tid >> 6, f = tid & 63;
    atomicAdd(&agg[(size_t)dst[e] * NF + f], feats[(size_t)src[e] * NF + f]);
}

__global__ __launch_bounds__(256) void layer1_fb_kernel(const float* __restrict__ x,
                                                        const float* __restrict__ agg,
                                                        const float* __restrict__ deg,
                                                        const float* __restrict__ Wself,
                                                        const float* __restrict__ Wneigh,
                                                        const float* __restrict__ b,
                                                        float* __restrict__ h1, int N) {
    int tid = blockIdx.x * blockDim.x + threadIdx.x;
    if (tid >= N * NF) return;
    int n = tid >> 6, c = tid & 63;
    float inv = 1.0f / fmaxf(deg[n], 1.0f);
    const float* xrow = x + (size_t)n * NF;
    const float* arow = agg + (size_t)n * NF;
    float acc = b[c];
    #pragma unroll
    for (int k = 0; k < NF; ++k) {
        acc += xrow[k] * Wself[k * NF + c];
        acc += (arow[k] * inv) * Wneigh[k * NF + c];
    }
    h1[tid] = fmaxf(acc, 0.f);
}

__global__ __launch_bounds__(256) void layer2_fb_kernel(const float* __restrict__ h1,
                                                        const float* __restrict__ agg,
                                                        const float* __restrict__ deg,
                                                        const float* __restrict__ Wself,
                                                        const float* __restrict__ Wneigh,
                                                        const float* __restrict__ b,
                                                        float* __restrict__ out, int N) {
    int tid = blockIdx.x * blockDim.x + threadIdx.x;
    if (tid >= N * 32) return;
    int n = tid >> 5, c = tid & 31;
    float inv = 1.0f / fmaxf(deg[n], 1.0f);
    const float* hrow = h1 + (size_t)n * NF;
    const float* arow = agg + (size_t)n * NF;
    float acc = b[c];
    #pragma unroll
    for (int k = 0; k < NF; ++k) {
        acc += hrow[k] * Wself[k * 32 + c];
        acc += (arow[k] * inv) * Wneigh[k * 32 + c];
    }
    out[tid] = acc;
}

// ---------------- launch ----------------

extern "C" void kernel_launch(void* const* d_in, const int* in_sizes, int n_in,
                              void* d_out, int out_size, void* d_ws, size_t ws_size,
                              hipStream_t stream) {
    const float* x        = (const float*)d_in[0];
    const int*   src      = (const int*)d_in[1];
    const int*   dst      = (const int*)d_in[2];
    const float* W_self1  = (const float*)d_in[3];
    const float* W_neigh1 = (const float*)d_in[4];
    const float* b1       = (const float*)d_in[5];
    const float* W_self2  = (const float*)d_in[6];
    const float* W_neigh2 = (const float*)d_in[7];
    const float* b2       = (const float*)d_in[8];
    float* out = (float*)d_out;

    const int N = in_sizes[0] / NF;   // 100000
    const int E = in_sizes[1];        // 1250000
    const int nb = (N + SB - 1) / SB; // 391, must be <= 1024
    const int nranges = (N + RMAX - 1) / RMAX;   // 8

    // ws layout (fast path); every segment 16B-aligned
    const size_t rsPad = ((size_t)N + 8) & ~7ull;
    int* row_start = (int*)d_ws;
    int* bsums     = row_start + rsPad;               // [1024]
    int* cursor    = bsums + 1024;                    // [N] (counts scratch)
    int* csr_src   = cursor + (((size_t)N + 7) & ~7ull);
    unsigned short* wt1h = (unsigned short*)(csr_src + (((size_t)E + 7) & ~7ull));
    unsigned short* wt1l = wt1h + 128 * 72;
    unsigned short* wt2h = wt1l + 128 * 72;
    unsigned short* wt2l = wt2h + 64 * 72;
    float* bufA = (float*)(wt2l + 64 * 72);           // xs -> h1 (f32, in place)
    // region B (aliased): t1n bf16 [N][64] (layer1), then s2 f32 [N][32] + t2n bf16 [N][32]
    char* regB = (char*)(bufA + (size_t)N * NF);
    unsigned short* t1n = (unsigned short*)regB;
    float*          s2  = (float*)regB;
    unsigned short* t2n = (unsigned short*)(regB + (size_t)N * 32 * sizeof(float));
    size_t regBsz = (size_t)N * 32 * sizeof(float) + (size_t)N * 32 * sizeof(unsigned short);
    if ((size_t)N * 64 * sizeof(unsigned short) > regBsz) regBsz = (size_t)N * 64 * sizeof(unsigned short);
    size_t need = (size_t)(regB - (char*)d_ws) + regBsz;

    if (ws_size >= need && nb <= 1024 && nranges >= 1) {
        // CSR build
        hipMemsetAsync(cursor, 0, (size_t)N * sizeof(int), stream);
        hist_lds_kernel<<<dim3(HIST_CHUNKS, nranges), 256, 0, stream>>>(dst, cursor, E, N);
        scan_block_kernel<<<nb, SB, 0, stream>>>(cursor, row_start, bsums, N);
        scan_tops_kernel<<<1, 1024, 0, stream>>>(bsums, nb);
        scan_final_kernel<<<(N + 255) / 256, 256, 0, stream>>>(row_start, bsums, cursor, N, E);
        scatter_part_kernel<<<dim3(SCAT_CHUNKS, nranges), 256, 0, stream>>>(src, dst, cursor,
                                                                            csr_src, E);
        // weight prep (independent of CSR)
        wprep_kernel<<<(128 * 64 + 64 * 64 + 255) / 256, 256, 0, stream>>>(
            W_self1, W_neigh1, W_self2, W_neigh2, wt1h, wt1l, wt2h, wt2l);

        int dblocks = (N + 127) / 128;
        // layer 1
        dense_mfma_kernel<8, 4><<<dblocks, 256, 0, stream>>>(x, wt1h, wt1l, b1,
                                                             bufA, t1n, 64, 64, N);
        agg64_kernel<<<(N * 64 + 255) / 256, 256, 0, stream>>>(t1n, bufA,
                                                               row_start, csr_src, N);
        // layer 2
        dense_mfma_kernel<4, 2><<<dblocks, 256, 0, stream>>>(bufA, wt2h, wt2l, b2,
                                                             s2, t2n, 32, 32, N);
        agg32_kernel<<<(N * 64 + 255) / 256, 256, 0, stream>>>(s2, t2n, row_start,
                                                               csr_src, out, N);
    } else {
        // fallback: atomic path (~51.6 MB)
        float* deg = (float*)d_ws;
        float* agg = deg + N;
        float* h1  = agg + (size_t)N * NF;
        hipMemsetAsync(deg, 0, (size_t)(N + (size_t)N * NF) * sizeof(float), stream);
        deg_kernel<<<(E + 255) / 256, 256, 0, stream>>>(dst, deg, E);
        int at = E * NF;
        agg_atomic_kernel<<<(at + 255) / 256, 256, 0, stream>>>(x, src, dst, agg, E);
        layer1_fb_kernel<<<(N * NF + 255) / 256, 256, 0, stream>>>(x, agg, deg, W_self1,
                                                                   W_neigh1, b1, h1, N);
        hipMemsetAsync(agg, 0, (size_t)N * NF * sizeof(float), stream);
        agg_atomic_kernel<<<(at + 255) / 256, 256, 0, stream>>>(h1, src, dst, agg, E);
        layer2_fb_kernel<<<(N * 32 + 255) / 256, 256, 0, stream>>>(h1, agg, deg, W_self2,
                                                                   W_neigh2, b2, out, N);
    }
}

// Round 6
// 256.562 us; speedup vs baseline: 3.7185x; 1.3972x over previous
//
#include <hip/hip_runtime.h>
#include <hip/hip_bf16.h>

// GraphSAGE 2-layer forward. N=100000, E=1250000, 64 -> 64 -> 32, fp32.
//
// Round-6: two-phase counting-sort CSR build. Round-5 lesson: a scatter window
// written by blocks on MULTIPLE XCDs gets ~17x writeback amplification (per-XCD
// L2s are non-coherent; partially-dirty lines each write back). Fix: bucket
// edges first (p1, coalesced-ish block-private writes), then ONE block owns one
// bucket's csr window exclusively (p2) -> every line written back once.
//
//   p1      : bucket edges by dst>>9 into per-bucket regions, (src<<9)|rel
//   bscan   : exclusive prefix of bucket sizes -> csr bases
//   p2      : per-bucket LDS count+scan -> row_start segment + csr scatter
//   dense1  : bufA = x@Ws1+b1 (f32), t1n = bf16(x@Wn1)     (MFMA split-bf16)
//   agg64   : bufA = relu(bufA + mean_n t1n[src])
//   dense2  : s2 = h1@Ws2+b2 (f32), t2n = bf16(h1@Wn2)
//   agg32   : out = s2 + mean_n t2n[src]

#define NF 64
#define BW 512            // bucket width (nodes); rel = dst & 511
#define MAXB 512          // max buckets supported by LDS arrays
#define CAPMAX 16384      // max edges per bucket region (mean 6378, >100 sigma)
#define P1_CHUNK 4096

typedef __attribute__((ext_vector_type(8))) short short8;
typedef __attribute__((ext_vector_type(8))) unsigned short ushort8v;
typedef __attribute__((ext_vector_type(4))) float floatx4;

__device__ __forceinline__ short bf16hi(float v) {
    __hip_bfloat16 h = __float2bfloat16(v);
    return *(short*)&h;
}
__device__ __forceinline__ float bf2f(short s) {
    __hip_bfloat16 h = *(__hip_bfloat16*)&s;
    return __bfloat162float(h);
}
__device__ __forceinline__ float bits2f(unsigned short u) {
    unsigned int x = ((unsigned int)u) << 16;
    union { unsigned int i; float f; } c; c.i = x; return c.f;
}

// ---------------- CSR build: counting sort ----------------

// p1: bucket the edge list. grid = ceil(E / P1_CHUNK)
__global__ __launch_bounds__(256) void p1_bucket_kernel(const int* __restrict__ src,
                                                        const int* __restrict__ dst,
                                                        int* __restrict__ gcursor,
                                                        unsigned* __restrict__ bucket,
                                                        int E, int nbuckets) {
    __shared__ int cnt[MAXB];
    __shared__ int cbase[MAXB];
    const int beg = blockIdx.x * P1_CHUNK;
    const int end = min(E, beg + P1_CHUNK);
    for (int i = threadIdx.x; i < nbuckets; i += 256) cnt[i] = 0;
    __syncthreads();
    for (int e = beg + threadIdx.x; e < end; e += 256)
        atomicAdd(&cnt[dst[e] >> 9], 1);
    __syncthreads();
    for (int i = threadIdx.x; i < nbuckets; i += 256) {
        int c = cnt[i];
        cbase[i] = c ? atomicAdd(&gcursor[i], c) : 0;
        cnt[i] = 0;                              // reuse as local cursor
    }
    __syncthreads();
    for (int e = beg + threadIdx.x; e < end; e += 256) {
        int d = dst[e];
        int r = d >> 9;
        int p = cbase[r] + atomicAdd(&cnt[r], 1);
        if (p < CAPMAX)                          // clamp: no OOB even if skewed
            bucket[(size_t)r * CAPMAX + p] = ((unsigned)src[e] << 9) | (unsigned)(d & (BW - 1));
    }
}

// exclusive prefix over bucket sizes -> rbase. single block.
__global__ __launch_bounds__(256) void bucket_scan_kernel(const int* __restrict__ gcursor,
                                                          int* __restrict__ rbase, int nbuckets) {
    __shared__ int buf[MAXB];
    int tid = threadIdx.x;
    for (int i = tid; i < MAXB; i += 256)
        buf[i] = (i < nbuckets) ? min(gcursor[i], CAPMAX) : 0;
    __syncthreads();
    for (int off = 1; off < MAXB; off <<= 1) {
        int v0 = (tid >= off) ? buf[tid - off] : 0;
        int i1 = tid + 256;
        int v1 = (i1 >= off) ? buf[i1 - off] : 0;
        __syncthreads();
        buf[tid] += v0;
        buf[i1] += v1;
        __syncthreads();
    }
    for (int i = tid; i < nbuckets; i += 256)
        rbase[i] = buf[i] - min(gcursor[i], CAPMAX);   // exclusive
}

// p2: one block per bucket. Exclusive ownership of row_start segment + csr window.
__global__ __launch_bounds__(256) void p2_csr_kernel(const unsigned* __restrict__ bucket,
                                                     const int* __restrict__ gcursor,
                                                     const int* __restrict__ rbase,
                                                     int* __restrict__ row_start,
                                                     int* __restrict__ csr_src,
                                                     int N, int E, int nbuckets) {
    __shared__ unsigned stage[CAPMAX];   // 64 KB
    __shared__ int cnt[BW];
    __shared__ int excl[BW];
    const int r = blockIdx.x;
    const int sz = min(gcursor[r], CAPMAX);
    const int base = rbase[r];
    const unsigned* bsrc = bucket + (size_t)r * CAPMAX;
    const int tid = threadIdx.x;

    for (int i = tid; i < BW; i += 256) cnt[i] = 0;
    __syncthreads();
    for (int i = tid; i < sz; i += 256) {
        unsigned v = bsrc[i];
        stage[i] = v;
        atomicAdd(&cnt[v & (BW - 1)], 1);
    }
    __syncthreads();
    // inclusive scan of cnt into excl (Hillis-Steele, 2 elems/thread)
    excl[tid] = cnt[tid];
    excl[tid + 256] = cnt[tid + 256];
    __syncthreads();
    for (int off = 1; off < BW; off <<= 1) {
        int v0 = (tid >= off) ? excl[tid - off] : 0;
        int i1 = tid + 256;
        int v1 = (i1 >= off) ? excl[i1 - off] : 0;
        __syncthreads();
        excl[tid] += v0;
        excl[i1] += v1;
        __syncthreads();
    }
    // row_start segment (exclusive = inclusive - count)
    for (int i = tid; i < BW; i += 256) {
        int node = r * BW + i;
        if (node < N) row_start[node] = base + excl[i] - cnt[i];
    }
    if (r == nbuckets - 1 && tid == 0) row_start[N] = E;
    __syncthreads();
    for (int i = tid; i < BW; i += 256) cnt[i] = excl[i] - cnt[i];  // cursors
    __syncthreads();
    for (int i = tid; i < sz; i += 256) {
        unsigned v = stage[i];
        int p = atomicAdd(&cnt[v & (BW - 1)], 1);
        csr_src[base + p] = (int)(v >> 9);       // window owned by this block only
    }
}

// ---------------- weight prep: transpose + split-bf16, [n][72] ----------------

__global__ __launch_bounds__(256) void wprep_kernel(const float* __restrict__ Ws1,
                                                    const float* __restrict__ Wn1,
                                                    const float* __restrict__ Ws2,
                                                    const float* __restrict__ Wn2,
                                                    unsigned short* __restrict__ wt1h,
                                                    unsigned short* __restrict__ wt1l,
                                                    unsigned short* __restrict__ wt2h,
                                                    unsigned short* __restrict__ wt2l) {
    int i = blockIdx.x * 256 + threadIdx.x;
    if (i < 128 * 64) {
        int n = i >> 6, k = i & 63;
        float v = (n < 64) ? Ws1[k * 64 + n] : Wn1[k * 64 + (n - 64)];
        short hi = bf16hi(v);
        wt1h[n * 72 + k] = (unsigned short)hi;
        wt1l[n * 72 + k] = (unsigned short)bf16hi(v - bf2f(hi));
    } else if (i < 128 * 64 + 64 * 64) {
        int j = i - 128 * 64;
        int n = j >> 6, k = j & 63;
        float v = (n < 32) ? Ws2[k * 32 + n] : Wn2[k * 32 + (n - 32)];
        short hi = bf16hi(v);
        wt2h[n * 72 + k] = (unsigned short)hi;
        wt2l[n * 72 + k] = (unsigned short)bf16hi(v - bf2f(hi));
    }
}

// ---------------- MFMA dense: [N][64] @ [64][NT*16] ----------
// A layout: A[m=lane&15][k=(lane>>4)*8+j]; C/D: col=lane&15, row=(lane>>4)*4+reg.
// Tiles t<NSELF -> f32 out + bias; t>=NSELF -> bf16 out (neighbor transform).

template<int NT, int NSELF>
__global__ __launch_bounds__(256) void dense_mfma_kernel(
        const float* __restrict__ X,                 // [N][64]
        const unsigned short* __restrict__ wh,       // [NT*16][72] bf16-hi
        const unsigned short* __restrict__ wl,       // [NT*16][72] bf16-lo
        const float* __restrict__ bias,              // [NSELF*16]
        float* __restrict__ outA,                    // row stride sA
        unsigned short* __restrict__ outB,           // row stride sB (bf16 bits)
        int sA, int sB, int N) {
    const int lane = threadIdx.x & 63;
    const int wid  = threadIdx.x >> 6;
    const int m = lane & 15, quad = lane >> 4;
    const int rowblk = blockIdx.x * 128 + wid * 32;

    floatx4 acc[2][NT];
    #pragma unroll
    for (int rt = 0; rt < 2; ++rt)
        #pragma unroll
        for (int t = 0; t < NT; ++t) acc[rt][t] = (floatx4)(0.f);

    short8 ah[2][2], al[2][2];   // [rowset][k-half]
    #pragma unroll
    for (int rt = 0; rt < 2; ++rt) {
        int r = rowblk + rt * 16 + m;
        if (r >= N) r = N - 1;                       // clamped load, store guarded
        const float* xp = X + (size_t)r * 64 + quad * 8;
        #pragma unroll
        for (int h = 0; h < 2; ++h) {
            floatx4 f0 = *(const floatx4*)(xp + h * 32);
            floatx4 f1 = *(const floatx4*)(xp + h * 32 + 4);
            short8 hi, lo;
            #pragma unroll
            for (int j = 0; j < 4; ++j) {
                short hv = bf16hi(f0[j]);
                hi[j] = hv; lo[j] = bf16hi(f0[j] - bf2f(hv));
                short hv2 = bf16hi(f1[j]);
                hi[4 + j] = hv2; lo[4 + j] = bf16hi(f1[j] - bf2f(hv2));
            }
            ah[rt][h] = hi; al[rt][h] = lo;
        }
    }

    #pragma unroll
    for (int t = 0; t < NT; ++t) {
        int n = t * 16 + m;
        const unsigned short* ph = wh + n * 72 + quad * 8;
        const unsigned short* pl = wl + n * 72 + quad * 8;
        #pragma unroll
        for (int h = 0; h < 2; ++h) {
            short8 bh = *(const short8*)(ph + h * 32);
            short8 bl = *(const short8*)(pl + h * 32);
            #pragma unroll
            for (int rt = 0; rt < 2; ++rt) {
                acc[rt][t] = __builtin_amdgcn_mfma_f32_16x16x32_bf16(ah[rt][h], bh, acc[rt][t], 0, 0, 0);
                acc[rt][t] = __builtin_amdgcn_mfma_f32_16x16x32_bf16(al[rt][h], bh, acc[rt][t], 0, 0, 0);
                acc[rt][t] = __builtin_amdgcn_mfma_f32_16x16x32_bf16(ah[rt][h], bl, acc[rt][t], 0, 0, 0);
            }
        }
    }

    #pragma unroll
    for (int rt = 0; rt < 2; ++rt) {
        #pragma unroll
        for (int t = 0; t < NT; ++t) {
            #pragma unroll
            for (int r4 = 0; r4 < 4; ++r4) {
                int row = rowblk + rt * 16 + quad * 4 + r4;
                if (row < N) {
                    if (t < NSELF) {
                        int col = t * 16 + m;
                        outA[(size_t)row * sA + col] = acc[rt][t][r4] + bias[col];
                    } else {
                        int col = (t - NSELF) * 16 + m;
                        outB[(size_t)row * sB + col] = (unsigned short)bf16hi(acc[rt][t][r4]);
                    }
                }
            }
        }
    }
}

// ---------------- CSR aggregation (bf16 gathers, wide waves) ----------------

// bufA[n] = relu(bufA[n] + mean_s t1n[s]); 8 groups of 8 lanes, 8 rows in flight
__global__ __launch_bounds__(256) void agg64_kernel(const unsigned short* __restrict__ t1n,
                                                    float* __restrict__ xs_io,
                                                    const int* __restrict__ row_start,
                                                    const int* __restrict__ csr_src, int N) {
    int n = (blockIdx.x * blockDim.x + threadIdx.x) >> 6;
    if (n >= N) return;
    int lane = threadIdx.x & 63;
    int g = lane >> 3, c = lane & 7;                 // lane covers feats c*8..c*8+7
    int beg = row_start[n], end = row_start[n + 1];
    float acc[8] = {0.f, 0.f, 0.f, 0.f, 0.f, 0.f, 0.f, 0.f};
    for (int j0 = beg; j0 < end; j0 += 8) {
        int j = j0 + g;
        if (j < end) {
            int s = csr_src[j];
            ushort8v u = *(const ushort8v*)(t1n + (size_t)s * 64 + c * 8);
            #pragma unroll
            for (int i = 0; i < 8; ++i) acc[i] += bits2f(u[i]);
        }
    }
    #pragma unroll
    for (int i = 0; i < 8; ++i) {
        float v = acc[i];
        v += __shfl_xor(v, 8);
        v += __shfl_xor(v, 16);
        v += __shfl_xor(v, 32);
        acc[i] = v;
    }
    if (g == 0) {
        float inv = 1.0f / fmaxf((float)(end - beg), 1.0f);
        size_t o = (size_t)n * 64 + c * 8;
        floatx4 x0 = *(const floatx4*)(xs_io + o);
        floatx4 x1 = *(const floatx4*)(xs_io + o + 4);
        floatx4 r0, r1;
        #pragma unroll
        for (int i = 0; i < 4; ++i) {
            r0[i] = fmaxf(x0[i] + acc[i] * inv, 0.f);
            r1[i] = fmaxf(x1[i] + acc[4 + i] * inv, 0.f);
        }
        *(floatx4*)(xs_io + o) = r0;
        *(floatx4*)(xs_io + o + 4) = r1;
    }
}

// out[n] = s2[n] + mean_s t2n[s]; 16 groups of 4 lanes, 16 rows in flight
__global__ __launch_bounds__(256) void agg32_kernel(const float* __restrict__ s2,
                                                    const unsigned short* __restrict__ t2n,
                                                    const int* __restrict__ row_start,
                                                    const int* __restrict__ csr_src,
                                                    float* __restrict__ out, int N) {
    int n = (blockIdx.x * blockDim.x + threadIdx.x) >> 6;
    if (n >= N) return;
    int lane = threadIdx.x & 63;
    int g = lane >> 2, c = lane & 3;                 // lane covers feats c*8..c*8+7
    int beg = row_start[n], end = row_start[n + 1];
    float acc[8] = {0.f, 0.f, 0.f, 0.f, 0.f, 0.f, 0.f, 0.f};
    for (int j0 = beg; j0 < end; j0 += 16) {
        int j = j0 + g;
        if (j < end) {
            int s = csr_src[j];
            ushort8v u = *(const ushort8v*)(t2n + (size_t)s * 32 + c * 8);
            #pragma unroll
            for (int i = 0; i < 8; ++i) acc[i] += bits2f(u[i]);
        }
    }
    #pragma unroll
    for (int i = 0; i < 8; ++i) {
        float v = acc[i];
        v += __shfl_xor(v, 4);
        v += __shfl_xor(v, 8);
        v += __shfl_xor(v, 16);
        v += __shfl_xor(v, 32);
        acc[i] = v;
    }
    if (g == 0) {
        float inv = 1.0f / fmaxf((float)(end - beg), 1.0f);
        size_t o = (size_t)n * 32 + c * 8;
        floatx4 s0 = *(const floatx4*)(s2 + o);
        floatx4 s1 = *(const floatx4*)(s2 + o + 4);
        floatx4 r0, r1;
        #pragma unroll
        for (int i = 0; i < 4; ++i) {
            r0[i] = s0[i] + acc[i] * inv;
            r1[i] = s1[i] + acc[4 + i] * inv;
        }
        *(floatx4*)(out + o) = r0;
        *(floatx4*)(out + o + 4) = r1;
    }
}

// ---------------- fallback (round-2 atomic path) ----------------

__global__ __launch_bounds__(256) void deg_kernel(const int* __restrict__ dst,
                                                  float* __restrict__ deg, int E) {
    int e = blockIdx.x * blockDim.x + threadIdx.x;
    if (e < E) atomicAdd(&deg[dst[e]], 1.0f);
}

__global__ __launch_bounds__(256) void agg_atomic_kernel(const float* __restrict__ feats,
                                                         const int* __restrict__ src,
                                                         const int* __restrict__ dst,
                                                         float* __restrict__ agg, int E) {
    int tid = blockIdx.x * blockDim.x + threadIdx.x;
    if (tid >= E * NF) return;
    int e = tid >> 6, f = tid & 63;
    atomicAdd(&agg[(size_t)dst[e] * NF + f], feats[(size_t)src[e] * NF + f]);
}

__global__ __launch_bounds__(256) void layer1_fb_kernel(const float* __restrict__ x,
                                                        const float* __restrict__ agg,
                                                        const float* __restrict__ deg,
                                                        const float* __restrict__ Wself,
                                                        const float* __restrict__ Wneigh,
                                                        const float* __restrict__ b,
                                                        float* __restrict__ h1, int N) {
    int tid = blockIdx.x * blockDim.x + threadIdx.x;
    if (tid >= N * NF) return;
    int n = tid >> 6, c = tid & 63;
    float inv = 1.0f / fmaxf(deg[n], 1.0f);
    const float* xrow = x + (size_t)n * NF;
    const float* arow = agg + (size_t)n * NF;
    float acc = b[c];
    #pragma unroll
    for (int k = 0; k < NF; ++k) {
        acc += xrow[k] * Wself[k * NF + c];
        acc += (arow[k] * inv) * Wneigh[k * NF + c];
    }
    h1[tid] = fmaxf(acc, 0.f);
}

__global__ __launch_bounds__(256) void layer2_fb_kernel(const float* __restrict__ h1,
                                                        const float* __restrict__ agg,
                                                        const float* __restrict__ deg,
                                                        const float* __restrict__ Wself,
                                                        const float* __restrict__ Wneigh,
                                                        const float* __restrict__ b,
                                                        float* __restrict__ out, int N) {
    int tid = blockIdx.x * blockDim.x + threadIdx.x;
    if (tid >= N * 32) return;
    int n = tid >> 5, c = tid & 31;
    float inv = 1.0f / fmaxf(deg[n], 1.0f);
    const float* hrow = h1 + (size_t)n * NF;
    const float* arow = agg + (size_t)n * NF;
    float acc = b[c];
    #pragma unroll
    for (int k = 0; k < NF; ++k) {
        acc += hrow[k] * Wself[k * 32 + c];
        acc += (arow[k] * inv) * Wneigh[k * 32 + c];
    }
    out[tid] = acc;
}

// ---------------- launch ----------------

extern "C" void kernel_launch(void* const* d_in, const int* in_sizes, int n_in,
                              void* d_out, int out_size, void* d_ws, size_t ws_size,
                              hipStream_t stream) {
    const float* x        = (const float*)d_in[0];
    const int*   src      = (const int*)d_in[1];
    const int*   dst      = (const int*)d_in[2];
    const float* W_self1  = (const float*)d_in[3];
    const float* W_neigh1 = (const float*)d_in[4];
    const float* b1       = (const float*)d_in[5];
    const float* W_self2  = (const float*)d_in[6];
    const float* W_neigh2 = (const float*)d_in[7];
    const float* b2       = (const float*)d_in[8];
    float* out = (float*)d_out;

    const int N = in_sizes[0] / NF;          // 100000
    const int E = in_sizes[1];               // 1250000
    const int nbuckets = (N + BW - 1) / BW;  // 196

    // ws layout; every segment 16B-aligned
    const size_t rsPad = ((size_t)N + 8) & ~7ull;
    int* row_start = (int*)d_ws;
    int* gcursor   = row_start + rsPad;               // [MAXB]
    int* rbase     = gcursor + MAXB;                  // [MAXB]
    int* csr_src   = rbase + MAXB;                    // [E]
    unsigned short* wt1h = (unsigned short*)(csr_src + (((size_t)E + 7) & ~7ull));
    unsigned short* wt1l = wt1h + 128 * 72;
    unsigned short* wt2h = wt1l + 128 * 72;
    unsigned short* wt2l = wt2h + 64 * 72;
    float* bufA = (float*)(wt2l + 64 * 72);           // xs -> h1 (f32); aliases bucket buf
    unsigned* bucket = (unsigned*)bufA;               // [nbuckets][CAPMAX], dead before dense1
    // region B (aliased): t1n bf16 [N][64] (layer1), then s2 f32 [N][32] + t2n bf16 [N][32]
    char* regB = (char*)(bufA + (size_t)N * NF);
    unsigned short* t1n = (unsigned short*)regB;
    float*          s2  = (float*)regB;
    unsigned short* t2n = (unsigned short*)(regB + (size_t)N * 32 * sizeof(float));
    size_t regBsz = (size_t)N * 32 * sizeof(float) + (size_t)N * 32 * sizeof(unsigned short);
    if ((size_t)N * 64 * sizeof(unsigned short) > regBsz) regBsz = (size_t)N * 64 * sizeof(unsigned short);
    size_t need = (size_t)(regB - (char*)d_ws) + regBsz;

    bool fast = ws_size >= need
             && nbuckets <= MAXB
             && (size_t)nbuckets * CAPMAX <= (size_t)N * NF      // bucket fits in bufA alias
             && (size_t)E * 2 / (size_t)nbuckets <= CAPMAX       // 2x headroom over mean
             && N < (1 << 23);                                   // src fits in 23 bits

    if (fast) {
        // CSR build (counting sort)
        hipMemsetAsync(gcursor, 0, MAXB * sizeof(int), stream);
        p1_bucket_kernel<<<(E + P1_CHUNK - 1) / P1_CHUNK, 256, 0, stream>>>(
            src, dst, gcursor, bucket, E, nbuckets);
        bucket_scan_kernel<<<1, 256, 0, stream>>>(gcursor, rbase, nbuckets);
        p2_csr_kernel<<<nbuckets, 256, 0, stream>>>(bucket, gcursor, rbase,
                                                    row_start, csr_src, N, E, nbuckets);
        // weight prep (independent)
        wprep_kernel<<<(128 * 64 + 64 * 64 + 255) / 256, 256, 0, stream>>>(
            W_self1, W_neigh1, W_self2, W_neigh2, wt1h, wt1l, wt2h, wt2l);

        int dblocks = (N + 127) / 128;
        // layer 1
        dense_mfma_kernel<8, 4><<<dblocks, 256, 0, stream>>>(x, wt1h, wt1l, b1,
                                                             bufA, t1n, 64, 64, N);
        agg64_kernel<<<(N * 64 + 255) / 256, 256, 0, stream>>>(t1n, bufA,
                                                               row_start, csr_src, N);
        // layer 2
        dense_mfma_kernel<4, 2><<<dblocks, 256, 0, stream>>>(bufA, wt2h, wt2l, b2,
                                                             s2, t2n, 32, 32, N);
        agg32_kernel<<<(N * 64 + 255) / 256, 256, 0, stream>>>(s2, t2n, row_start,
                                                               csr_src, out, N);
    } else {
        // fallback: atomic path (~51.6 MB)
        float* deg = (float*)d_ws;
        float* agg = deg + N;
        float* h1  = agg + (size_t)N * NF;
        hipMemsetAsync(deg, 0, (size_t)(N + (size_t)N * NF) * sizeof(float), stream);
        deg_kernel<<<(E + 255) / 256, 256, 0, stream>>>(dst, deg, E);
        int at = E * NF;
        agg_atomic_kernel<<<(at + 255) / 256, 256, 0, stream>>>(x, src, dst, agg, E);
        layer1_fb_kernel<<<(N * NF + 255) / 256, 256, 0, stream>>>(x, agg, deg, W_self1,
                                                                   W_neigh1, b1, h1, N);
        hipMemsetAsync(agg, 0, (size_t)N * NF * sizeof(float), stream);
        agg_atomic_kernel<<<(at + 255) / 256, 256, 0, stream>>>(h1, src, dst, agg, E);
        layer2_fb_kernel<<<(N * 32 + 255) / 256, 256, 0, stream>>>(h1, agg, deg, W_self2,
                                                                   W_neigh2, b2, out, N);
    }
}